// Round 9
// baseline (490.204 us; speedup 1.0000x reference)
//
#include <hip/hip_runtime.h>
#include <hip/hip_bf16.h>

#define N_NODES 50000
#define N_EDGES 800000
#define NODE_F  128
#define EDGE_F  64
#define OUT_F   128

#define NCH ((N_NODES + 255) / 256)      // 196 scan chunks
// Balanced ranges: NRANGES = 2 * (EDGE_BLOCKS * 2) so every wave-pair owns
// exactly 2 ranges (~112 edges each), proportional boundaries snapped to
// dst-row starts. Grid 1792 = 7 blocks/CU exactly (bound 7: 28 waves/CU).
#define NRANGES 7168
#define EDGE_BLOCKS 1792

typedef __attribute__((ext_vector_type(8))) short short8;
typedef __attribute__((ext_vector_type(4))) short short4v;
typedef __attribute__((ext_vector_type(4))) float floatx4;

__device__ __forceinline__ unsigned short f2bf(float f) {
    unsigned int u = __float_as_uint(f);
    u += 0x7fffu + ((u >> 16) & 1u);
    return (unsigned short)(u >> 16);
}

// packed RNE convert: 8 floats -> short8 bf16 via v_cvt_pk_bf16_f32
__device__ __forceinline__ short8 cvt8(floatx4 v0, floatx4 v1) {
    union { __hip_bfloat162 h[4]; short8 s; } u;
    u.h[0] = __float22bfloat162_rn(make_float2(v0[0], v0[1]));
    u.h[1] = __float22bfloat162_rn(make_float2(v0[2], v0[3]));
    u.h[2] = __float22bfloat162_rn(make_float2(v1[0], v1[1]));
    u.h[3] = __float22bfloat162_rn(make_float2(v1[2], v1[3]));
    return u.s;
}

// ---------------------------------------------------------------------------
// Kernel 1 (fused): blocks [0, NODE_BLOCKS) : Y[n][128] = x[n] @ W[64:192] + b
//                   blocks [NODE_BLOCKS, +HIST_BLOCKS) : dst-degree histogram
// ---------------------------------------------------------------------------
#define TILE_N1 32
#define N_NTILES ((N_NODES + TILE_N1 - 1) / TILE_N1)
#define LDS_STRIDE1 136
#define NODE_BLOCKS 782
#define HIST_BLOCKS 1024

__global__ __launch_bounds__(256, 4) void node_hist_kernel(
    const float* __restrict__ x,
    const float* __restrict__ W,
    const float* __restrict__ bias,
    float*       __restrict__ Y,
    const int*   __restrict__ edge_index,
    int*         __restrict__ hist)
{
    __shared__ __align__(16) unsigned short xs[TILE_N1][LDS_STRIDE1];

    if (blockIdx.x >= NODE_BLOCKS) {
        // ---- histogram part ----
        const int* __restrict__ dstp = edge_index + N_EDGES;
        const int stride = (gridDim.x - NODE_BLOCKS) * 256;
        for (int i = (blockIdx.x - NODE_BLOCKS) * 256 + threadIdx.x; i < N_EDGES;
             i += stride)
            atomicAdd(&hist[dstp[i]], 1);
        return;
    }

    // ---- node GEMM part ----
    const int tid  = threadIdx.x;
    const int wave = tid >> 6;
    const int lane = tid & 63;
    const int col  = lane & 15;
    const int quad = lane >> 4;
    const int wbase = wave * 32;

    const float* __restrict__ Wx = W + EDGE_F * OUT_F;

    short8 bfr[4][2];
    #pragma unroll
    for (int kc = 0; kc < 4; ++kc) {
        #pragma unroll
        for (int ns = 0; ns < 2; ++ns) {
            const int n = wbase + ns * 16 + col;
            const int krow = kc * 32 + quad * 8;
            short8 v;
            #pragma unroll
            for (int j = 0; j < 8; ++j)
                v[j] = (short)f2bf(Wx[(krow + j) * OUT_F + n]);
            bfr[kc][ns] = v;
        }
    }
    const float b0 = bias[wbase + col];
    const float b1 = bias[wbase + 16 + col];

    for (int tile = blockIdx.x; tile < N_NTILES; tile += NODE_BLOCKS) {
        const int n0 = tile * TILE_N1;
        {
            const int e   = tid >> 3;
            const int sub = tid & 7;
            const int node = n0 + e;
            const float* __restrict__ xr = x + (size_t)node * NODE_F;
            #pragma unroll
            for (int i = 0; i < 4; ++i) {
                const int fi = sub + 8 * i;
                floatx4 v = {0.f, 0.f, 0.f, 0.f};
                if (node < N_NODES) v = *(const floatx4*)(xr + fi * 4);
                union { __hip_bfloat162 h[2]; short4v s; } u;
                u.h[0] = __float22bfloat162_rn(make_float2(v[0], v[1]));
                u.h[1] = __float22bfloat162_rn(make_float2(v[2], v[3]));
                *(short4v*)&xs[e][fi * 4] = u.s;
            }
        }
        __syncthreads();

        floatx4 acc[2][2] = {};
        #pragma unroll
        for (int kc = 0; kc < 4; ++kc) {
            short8 a0 = *(const short8*)&xs[col     ][kc * 32 + quad * 8];
            short8 a1 = *(const short8*)&xs[16 + col][kc * 32 + quad * 8];
            acc[0][0] = __builtin_amdgcn_mfma_f32_16x16x32_bf16(a0, bfr[kc][0], acc[0][0], 0, 0, 0);
            acc[0][1] = __builtin_amdgcn_mfma_f32_16x16x32_bf16(a0, bfr[kc][1], acc[0][1], 0, 0, 0);
            acc[1][0] = __builtin_amdgcn_mfma_f32_16x16x32_bf16(a1, bfr[kc][0], acc[1][0], 0, 0, 0);
            acc[1][1] = __builtin_amdgcn_mfma_f32_16x16x32_bf16(a1, bfr[kc][1], acc[1][1], 0, 0, 0);
        }

        #pragma unroll
        for (int ms = 0; ms < 2; ++ms) {
            #pragma unroll
            for (int r = 0; r < 4; ++r) {
                const int m = ms * 16 + quad * 4 + r;
                const int node = n0 + m;
                if (node < N_NODES) {
                    float* yrow = Y + (size_t)node * OUT_F + wbase;
                    yrow[col]      = acc[ms][0][r] + b0;
                    yrow[16 + col] = acc[ms][1][r] + b1;
                }
            }
        }
        __syncthreads();
    }
}

// ---------------------------------------------------------------------------
// Counting sort by dst
// ---------------------------------------------------------------------------
__global__ void scan1_kernel(const int* __restrict__ hist, int* __restrict__ chunkSum) {
    __shared__ int s[256];
    const int c = blockIdx.x, t = threadIdx.x, idx = c * 256 + t;
    s[t] = (idx < N_NODES) ? hist[idx] : 0;
    __syncthreads();
    for (int off = 128; off > 0; off >>= 1) {
        if (t < off) s[t] += s[t + off];
        __syncthreads();
    }
    if (t == 0) chunkSum[c] = s[0];
}

// scan2 folded in: each block redundantly reduces chunkSum[0..c-1] (196 ints).
// Also zeroes out[] rows for zero-degree nodes (replaces the 25.6 MB memset).
__global__ void scan23_kernel(const int* __restrict__ hist, const int* __restrict__ chunkSum,
                              int* __restrict__ row_off, int* __restrict__ cursor,
                              float* __restrict__ out) {
    __shared__ int s[256];
    __shared__ int basev;
    const int c = blockIdx.x, t = threadIdx.x, idx = c * 256 + t;

    // exclusive chunk base = sum_{j<c} chunkSum[j]
    s[t] = (t < c) ? chunkSum[t] : 0;
    __syncthreads();
    for (int off = 128; off > 0; off >>= 1) {
        if (t < off) s[t] += s[t + off];
        __syncthreads();
    }
    if (t == 0) basev = s[0];
    __syncthreads();

    const int v = (idx < N_NODES) ? hist[idx] : 0;
    s[t] = v;
    __syncthreads();
    for (int off = 1; off < 256; off <<= 1) {
        int u = (t >= off) ? s[t - off] : 0;
        __syncthreads();
        s[t] += u;
        __syncthreads();
    }
    const int excl = s[t] - v + basev;
    if (idx < N_NODES) {
        row_off[idx] = excl;
        cursor[idx]  = excl;
        if (v == 0) {   // zero-degree node: edge_gemm never writes this row
            floatx4 z = {0.f, 0.f, 0.f, 0.f};
            float* o = out + (size_t)idx * OUT_F;
            #pragma unroll
            for (int i = 0; i < 32; ++i) *(floatx4*)(o + i * 4) = z;
        }
    }
    if (c == 0 && t == 0) row_off[N_NODES] = N_EDGES;
}

__device__ __forceinline__ int lbound(const int* __restrict__ ro, int target) {
    int lo = 0, hi = N_NODES;
    while (lo < hi) {
        const int mid = (lo + hi) >> 1;
        if (ro[mid] < target) lo = mid + 1; else hi = mid;
    }
    return lo;
}

// fused: blocks [0,32) compute range_start; blocks [32,+) scatter edges.
#define RS_RANGE_BLOCKS 32
#define RS_SCATTER_BLOCKS 2048
__global__ void range_scatter_kernel(const int* __restrict__ row_off,
                                     const int* __restrict__ edge_index,
                                     int* __restrict__ cursor,
                                     int* __restrict__ range_start,
                                     int2* __restrict__ sorted) {
    if (blockIdx.x < RS_RANGE_BLOCKS) {
        const int rg = blockIdx.x * 256 + threadIdx.x;
        if (rg <= NRANGES) {
            // proportional boundary, snapped to dst-row start
            const int tgt = (int)((long long)rg * N_EDGES / NRANGES);
            range_start[rg] = row_off[lbound(row_off, tgt)];
        }
        return;
    }
    const int* __restrict__ srcp = edge_index;
    const int* __restrict__ dstp = edge_index + N_EDGES;
    const int stride = (gridDim.x - RS_RANGE_BLOCKS) * 256;
    for (int i = (blockIdx.x - RS_RANGE_BLOCKS) * 256 + threadIdx.x; i < N_EDGES;
         i += stride) {
        const int d = dstp[i];
        const int p = atomicAdd(&cursor[d], 1);
        sorted[p] = make_int2(i, (int)(((unsigned)srcp[i] << 16) | (unsigned)d));
    }
}

// ---------------------------------------------------------------------------
// Kernel 2: dst-sorted edge GEMM (exact Round-4 inner loop, 1-deep prefetch).
//   - R8 post-mortem: 2-deep sorted prefetch = spill traffic (+20MB), +4.5us
//     -> REVERTED. The sorted-read was already hidden by the reduce.
//   - NEW: __launch_bounds__(256,7), grid 1792 = 7 blocks/CU, NRANGES 7168
//     (2 ranges per wave-pair). Reg budget 512/7=73 > ~64 live -> no spill;
//     +17% waves/SIMD to hide the exposed Y-gather/A-load latency.
//     (bound 8 = 64 budget spills, R5; bound 6 = 55% occ, latency exposed, R4)
// ---------------------------------------------------------------------------
__global__ __launch_bounds__(256, 7) void edge_gemm(
    const float* __restrict__ edge_attr,
    const float* __restrict__ W,
    const float* __restrict__ Y,
    const int*   __restrict__ range_start,
    const int2*  __restrict__ sorted,
    float*       __restrict__ out)
{
    __shared__ float CT[4][16][68];   // per-wave tile; quad bank-shift 16 -> free 2-way

    const int tid  = threadIdx.x;
    const int wave = tid >> 6;
    const int lane = tid & 63;
    const int col  = lane & 15;
    const int quad = lane >> 4;
    const int p    = wave & 1;        // col-half

    // B-frags for this wave's 64 cols: [2 kc][4 ns]
    short8 bfr[2][4];
    #pragma unroll
    for (int kc = 0; kc < 2; ++kc) {
        #pragma unroll
        for (int ns = 0; ns < 4; ++ns) {
            const int n = p * 64 + ns * 16 + col;
            const int krow = kc * 32 + quad * 8;
            short8 v;
            #pragma unroll
            for (int j = 0; j < 8; ++j)
                v[j] = (short)f2bf(W[(krow + j) * OUT_F + n]);
            bfr[kc][ns] = v;
        }
    }

    float* __restrict__ obase = out + p * 64 + lane;

    const int grange = blockIdx.x * 2 + (wave >> 1);
    const int stride = gridDim.x * 2;

    for (int rg = grange; rg < NRANGES; rg += stride) {
        const int eb = range_start[rg];
        const int ee = range_start[rg + 1];
        if (eb >= ee) continue;

        int   cur = -1;
        float s   = 0.f;

        // first tile's sorted entries + A-frags
        int2 me = sorted[min(eb + col, ee - 1)];
        short8 a[2];
        {
            const float* __restrict__ ar = edge_attr + (size_t)me.x * EDGE_F;
            #pragma unroll
            for (int kc = 0; kc < 2; ++kc)
                a[kc] = cvt8(*(const floatx4*)(ar + kc * 32 + quad * 8),
                             *(const floatx4*)(ar + kc * 32 + quad * 8 + 4));
        }

        for (int t0 = eb; t0 < ee; t0 += 16) {
            // ---- acc init = Y[src] gather for this wave's col-half ----
            floatx4 acc[4];
            #pragma unroll
            for (int r = 0; r < 4; ++r) {
                const int src = (int)((unsigned)__shfl(me.y, quad * 4 + r) >> 16);
                const float* __restrict__ yr = Y + (size_t)src * OUT_F + p * 64;
                #pragma unroll
                for (int ns = 0; ns < 4; ++ns)
                    acc[ns][r] = yr[ns * 16 + col];
            }

            // ---- MFMA: [16 edges x 64 cols], K=64 ----
            #pragma unroll
            for (int kc = 0; kc < 2; ++kc) {
                #pragma unroll
                for (int ns = 0; ns < 4; ++ns)
                    acc[ns] = __builtin_amdgcn_mfma_f32_16x16x32_bf16(a[kc], bfr[kc][ns], acc[ns], 0, 0, 0);
            }

            // ---- ReLU -> CT (pad rows write 0) ----
            #pragma unroll
            for (int r = 0; r < 4; ++r) {
                const bool rvalid = (t0 + quad * 4 + r) < ee;
                #pragma unroll
                for (int ns = 0; ns < 4; ++ns)
                    CT[wave][quad * 4 + r][ns * 16 + col] =
                        rvalid ? fmaxf(acc[ns][r], 0.f) : 0.f;
            }
            __builtin_amdgcn_wave_barrier();

            // ---- prefetch next tile's sorted entries (overlaps reduce) ----
            const int t1 = t0 + 16;
            int2 me2;
            if (t1 < ee) me2 = sorted[min(t1 + col, ee - 1)];

            // ---- reduce: batched LDS reads + uniform scalar flush ----
            float cv[16];
            #pragma unroll
            for (int m = 0; m < 16; ++m) cv[m] = CT[wave][m][lane];

            const int mez = me.y;
            #pragma unroll
            for (int m = 0; m < 16; ++m) {
                const int d = (int)((unsigned)__builtin_amdgcn_readlane(mez, m) & 0xffffu);
                if (d != cur) {
                    if (cur >= 0) obase[(size_t)cur * OUT_F] = s;
                    cur = d; s = 0.f;
                }
                s += cv[m];
            }
            cur = __builtin_amdgcn_readfirstlane(cur);
            __builtin_amdgcn_wave_barrier();

            // ---- next tile's A-frags ----
            if (t1 < ee) {
                me = me2;
                const float* __restrict__ ar = edge_attr + (size_t)me.x * EDGE_F;
                #pragma unroll
                for (int kc = 0; kc < 2; ++kc)
                    a[kc] = cvt8(*(const floatx4*)(ar + kc * 32 + quad * 8),
                                 *(const floatx4*)(ar + kc * 32 + quad * 8 + 4));
            }
        }
        if (cur >= 0) obase[(size_t)cur * OUT_F] = s;
    }
}

// ---------------------------------------------------------------------------
// Fallback (ws too small): atomic edge kernel
// ---------------------------------------------------------------------------
__global__ __launch_bounds__(256, 3) void edge_kernel_atomic(
    const float* __restrict__ edge_attr,
    const int*   __restrict__ edge_index,
    const float* __restrict__ W,
    const float* __restrict__ Y,
    float*       __restrict__ out)
{
    const int lane = threadIdx.x & 63;
    const int col  = lane & 15;
    const int quad = lane >> 4;

    short8 bfr[2][8];
    #pragma unroll
    for (int kc = 0; kc < 2; ++kc)
        #pragma unroll
        for (int ns = 0; ns < 8; ++ns) {
            const int n = ns * 16 + col;
            const int krow = kc * 32 + quad * 8;
            short8 v;
            #pragma unroll
            for (int j = 0; j < 8; ++j)
                v[j] = (short)f2bf(W[(krow + j) * OUT_F + n]);
            bfr[kc][ns] = v;
        }

    const int* __restrict__ srcp = edge_index;
    const int* __restrict__ dstp = edge_index + N_EDGES;

    const int gwave  = blockIdx.x * 4 + (threadIdx.x >> 6);
    const int nwaves = gridDim.x * 4;

    for (int t = gwave; t < N_EDGES / 16; t += nwaves) {
        const int e0 = t * 16;
        const float* __restrict__ ar = edge_attr + (size_t)(e0 + col) * EDGE_F;
        short8 a[2];
        #pragma unroll
        for (int kc = 0; kc < 2; ++kc)
            a[kc] = cvt8(*(const floatx4*)(ar + kc * 32 + quad * 8),
                         *(const floatx4*)(ar + kc * 32 + quad * 8 + 4));
        int sr[4], dr[4];
        #pragma unroll
        for (int r = 0; r < 4; ++r) {
            sr[r] = srcp[e0 + quad * 4 + r];
            dr[r] = dstp[e0 + quad * 4 + r];
        }
        floatx4 acc[8];
        #pragma unroll
        for (int ns = 0; ns < 8; ++ns)
            #pragma unroll
            for (int r = 0; r < 4; ++r)
                acc[ns][r] = Y[(size_t)sr[r] * OUT_F + ns * 16 + col];
        #pragma unroll
        for (int kc = 0; kc < 2; ++kc)
            #pragma unroll
            for (int ns = 0; ns < 8; ++ns)
                acc[ns] = __builtin_amdgcn_mfma_f32_16x16x32_bf16(a[kc], bfr[kc][ns], acc[ns], 0, 0, 0);
        #pragma unroll
        for (int ns = 0; ns < 8; ++ns)
            #pragma unroll
            for (int r = 0; r < 4; ++r) {
                const float v = acc[ns][r];
                if (v > 0.0f)
                    atomicAdd(out + (size_t)dr[r] * OUT_F + ns * 16 + col, v);
            }
    }
}

extern "C" void kernel_launch(void* const* d_in, const int* in_sizes, int n_in,
                              void* d_out, int out_size, void* d_ws, size_t ws_size,
                              hipStream_t stream) {
    const float* x          = (const float*)d_in[0];
    const int*   edge_index = (const int*)  d_in[1];
    const float* edge_attr  = (const float*)d_in[2];
    const float* W          = (const float*)d_in[3];
    const float* bias       = (const float*)d_in[4];
    float*       out        = (float*)d_out;

    // workspace layout
    float* Y          = (float*)d_ws;                          // 25.6 MB
    int2*  sorted     = (int2*)(Y + (size_t)N_NODES * OUT_F);  // 6.4 MB
    int*   hist       = (int*)(sorted + N_EDGES);
    int*   chunkSum   = hist + N_NODES;
    int*   chunkBase  = chunkSum + 256;
    int*   row_off    = chunkBase + 256;                       // N_NODES+1
    int*   cursor     = row_off + N_NODES + 1;                 // N_NODES
    int*   range_start= cursor + N_NODES;                      // NRANGES+1
    const size_t needed = (size_t)((char*)(range_start + NRANGES + 1) - (char*)d_ws);

    if (ws_size < needed) {
        hipMemsetAsync(out, 0, (size_t)out_size * sizeof(float), stream);
        node_hist_kernel<<<dim3(NODE_BLOCKS), dim3(256), 0, stream>>>(
            x, W, bias, Y, edge_index, (int*)nullptr);
        edge_kernel_atomic<<<dim3(1024), dim3(256), 0, stream>>>(edge_attr, edge_index, W, Y, out);
        return;
    }

    hipMemsetAsync(hist, 0, (size_t)N_NODES * sizeof(int), stream);
    node_hist_kernel<<<dim3(NODE_BLOCKS + HIST_BLOCKS), dim3(256), 0, stream>>>(
        x, W, bias, Y, edge_index, hist);
    scan1_kernel   <<<dim3(NCH), dim3(256), 0, stream>>>(hist, chunkSum);
    scan23_kernel  <<<dim3(NCH), dim3(256), 0, stream>>>(hist, chunkSum, row_off, cursor, out);
    range_scatter_kernel<<<dim3(RS_RANGE_BLOCKS + RS_SCATTER_BLOCKS), dim3(256), 0, stream>>>(
        row_off, edge_index, cursor, range_start, sorted);
    edge_gemm<<<dim3(EDGE_BLOCKS), dim3(256), 0, stream>>>(
        edge_attr, W, Y, range_start, sorted, out);
}

// Round 10
// 475.444 us; speedup vs baseline: 1.0310x; 1.0310x over previous
//
#include <hip/hip_runtime.h>
#include <hip/hip_bf16.h>

#define N_NODES 50000
#define N_EDGES 800000
#define NODE_F  128
#define EDGE_F  64
#define OUT_F   128

#define NCH ((N_NODES + 255) / 256)      // 196 scan chunks
// Balanced ranges: NRANGES = 2 * (EDGE_BLOCKS * 2) so every wave-pair owns
// exactly 2 ranges (~130 edges each), proportional boundaries snapped to
// dst-row starts. Grid 1536 = 6 blocks/CU exactly (Round-4 proven best).
#define NRANGES 6144
#define EDGE_BLOCKS 1536

typedef __attribute__((ext_vector_type(8))) short short8;
typedef __attribute__((ext_vector_type(4))) short short4v;
typedef __attribute__((ext_vector_type(4))) float floatx4;

__device__ __forceinline__ unsigned short f2bf(float f) {
    unsigned int u = __float_as_uint(f);
    u += 0x7fffu + ((u >> 16) & 1u);
    return (unsigned short)(u >> 16);
}

// packed RNE convert: 8 floats -> short8 bf16 via v_cvt_pk_bf16_f32
__device__ __forceinline__ short8 cvt8(floatx4 v0, floatx4 v1) {
    union { __hip_bfloat162 h[4]; short8 s; } u;
    u.h[0] = __float22bfloat162_rn(make_float2(v0[0], v0[1]));
    u.h[1] = __float22bfloat162_rn(make_float2(v0[2], v0[3]));
    u.h[2] = __float22bfloat162_rn(make_float2(v1[0], v1[1]));
    u.h[3] = __float22bfloat162_rn(make_float2(v1[2], v1[3]));
    return u.s;
}

// ---------------------------------------------------------------------------
// Kernel 1 (fused): blocks [0, NODE_BLOCKS) : Y[n][128] = x[n] @ W[64:192] + b
//                   blocks [NODE_BLOCKS, +HIST_BLOCKS) : dst-degree histogram
// ---------------------------------------------------------------------------
#define TILE_N1 32
#define N_NTILES ((N_NODES + TILE_N1 - 1) / TILE_N1)
#define LDS_STRIDE1 136
#define NODE_BLOCKS 782
#define HIST_BLOCKS 1024

__global__ __launch_bounds__(256, 4) void node_hist_kernel(
    const float* __restrict__ x,
    const float* __restrict__ W,
    const float* __restrict__ bias,
    float*       __restrict__ Y,
    const int*   __restrict__ edge_index,
    int*         __restrict__ hist)
{
    __shared__ __align__(16) unsigned short xs[TILE_N1][LDS_STRIDE1];

    if (blockIdx.x >= NODE_BLOCKS) {
        // ---- histogram part ----
        const int* __restrict__ dstp = edge_index + N_EDGES;
        const int stride = (gridDim.x - NODE_BLOCKS) * 256;
        for (int i = (blockIdx.x - NODE_BLOCKS) * 256 + threadIdx.x; i < N_EDGES;
             i += stride)
            atomicAdd(&hist[dstp[i]], 1);
        return;
    }

    // ---- node GEMM part ----
    const int tid  = threadIdx.x;
    const int wave = tid >> 6;
    const int lane = tid & 63;
    const int col  = lane & 15;
    const int quad = lane >> 4;
    const int wbase = wave * 32;

    const float* __restrict__ Wx = W + EDGE_F * OUT_F;

    short8 bfr[4][2];
    #pragma unroll
    for (int kc = 0; kc < 4; ++kc) {
        #pragma unroll
        for (int ns = 0; ns < 2; ++ns) {
            const int n = wbase + ns * 16 + col;
            const int krow = kc * 32 + quad * 8;
            short8 v;
            #pragma unroll
            for (int j = 0; j < 8; ++j)
                v[j] = (short)f2bf(Wx[(krow + j) * OUT_F + n]);
            bfr[kc][ns] = v;
        }
    }
    const float b0 = bias[wbase + col];
    const float b1 = bias[wbase + 16 + col];

    for (int tile = blockIdx.x; tile < N_NTILES; tile += NODE_BLOCKS) {
        const int n0 = tile * TILE_N1;
        {
            const int e   = tid >> 3;
            const int sub = tid & 7;
            const int node = n0 + e;
            const float* __restrict__ xr = x + (size_t)node * NODE_F;
            #pragma unroll
            for (int i = 0; i < 4; ++i) {
                const int fi = sub + 8 * i;
                floatx4 v = {0.f, 0.f, 0.f, 0.f};
                if (node < N_NODES) v = *(const floatx4*)(xr + fi * 4);
                union { __hip_bfloat162 h[2]; short4v s; } u;
                u.h[0] = __float22bfloat162_rn(make_float2(v[0], v[1]));
                u.h[1] = __float22bfloat162_rn(make_float2(v[2], v[3]));
                *(short4v*)&xs[e][fi * 4] = u.s;
            }
        }
        __syncthreads();

        floatx4 acc[2][2] = {};
        #pragma unroll
        for (int kc = 0; kc < 4; ++kc) {
            short8 a0 = *(const short8*)&xs[col     ][kc * 32 + quad * 8];
            short8 a1 = *(const short8*)&xs[16 + col][kc * 32 + quad * 8];
            acc[0][0] = __builtin_amdgcn_mfma_f32_16x16x32_bf16(a0, bfr[kc][0], acc[0][0], 0, 0, 0);
            acc[0][1] = __builtin_amdgcn_mfma_f32_16x16x32_bf16(a0, bfr[kc][1], acc[0][1], 0, 0, 0);
            acc[1][0] = __builtin_amdgcn_mfma_f32_16x16x32_bf16(a1, bfr[kc][0], acc[1][0], 0, 0, 0);
            acc[1][1] = __builtin_amdgcn_mfma_f32_16x16x32_bf16(a1, bfr[kc][1], acc[1][1], 0, 0, 0);
        }

        #pragma unroll
        for (int ms = 0; ms < 2; ++ms) {
            #pragma unroll
            for (int r = 0; r < 4; ++r) {
                const int m = ms * 16 + quad * 4 + r;
                const int node = n0 + m;
                if (node < N_NODES) {
                    float* yrow = Y + (size_t)node * OUT_F + wbase;
                    yrow[col]      = acc[ms][0][r] + b0;
                    yrow[16 + col] = acc[ms][1][r] + b1;
                }
            }
        }
        __syncthreads();
    }
}

// ---------------------------------------------------------------------------
// Merged scan (was scan1 + scan23): one pass, no chunkSum dependency.
// Each block independently re-reduces hist[0 .. c*256) for its chunk base
// (hist is 200 KB, L2-resident; all blocks run in parallel), then does the
// local 256-wide inclusive scan. Also zeroes out[] rows for zero-degree
// nodes (replaces the 25.6 MB output memset).
// ---------------------------------------------------------------------------
__global__ void scan_merged_kernel(const int* __restrict__ hist,
                                   int* __restrict__ row_off, int* __restrict__ cursor,
                                   float* __restrict__ out) {
    __shared__ int s[256];
    const int c = blockIdx.x, t = threadIdx.x, idx = c * 256 + t;

    // phase A: chunk base = sum(hist[0 .. c*256)) via block-wide reduce
    int part = 0;
    for (int i = t; i < c * 256; i += 256) part += hist[i];
    s[t] = part;
    __syncthreads();
    for (int off = 128; off > 0; off >>= 1) {
        if (t < off) s[t] += s[t + off];
        __syncthreads();
    }
    const int basev = s[0];
    __syncthreads();

    // phase B: local inclusive scan of this chunk
    const int v = (idx < N_NODES) ? hist[idx] : 0;
    s[t] = v;
    __syncthreads();
    for (int off = 1; off < 256; off <<= 1) {
        int u = (t >= off) ? s[t - off] : 0;
        __syncthreads();
        s[t] += u;
        __syncthreads();
    }
    const int excl = s[t] - v + basev;
    if (idx < N_NODES) {
        row_off[idx] = excl;
        cursor[idx]  = excl;
        if (v == 0) {   // zero-degree node: edge_gemm never writes this row
            floatx4 z = {0.f, 0.f, 0.f, 0.f};
            float* o = out + (size_t)idx * OUT_F;
            #pragma unroll
            for (int i = 0; i < 32; ++i) *(floatx4*)(o + i * 4) = z;
        }
    }
    if (c == 0 && t == 0) row_off[N_NODES] = N_EDGES;
}

__device__ __forceinline__ int lbound(const int* __restrict__ ro, int target) {
    int lo = 0, hi = N_NODES;
    while (lo < hi) {
        const int mid = (lo + hi) >> 1;
        if (ro[mid] < target) lo = mid + 1; else hi = mid;
    }
    return lo;
}

// fused: blocks [0,32) compute range_start; blocks [32,+) scatter edges.
#define RS_RANGE_BLOCKS 32
#define RS_SCATTER_BLOCKS 2048
__global__ void range_scatter_kernel(const int* __restrict__ row_off,
                                     const int* __restrict__ edge_index,
                                     int* __restrict__ cursor,
                                     int* __restrict__ range_start,
                                     int2* __restrict__ sorted) {
    if (blockIdx.x < RS_RANGE_BLOCKS) {
        const int rg = blockIdx.x * 256 + threadIdx.x;
        if (rg <= NRANGES) {
            // proportional boundary, snapped to dst-row start
            const int tgt = (int)((long long)rg * N_EDGES / NRANGES);
            range_start[rg] = row_off[lbound(row_off, tgt)];
        }
        return;
    }
    const int* __restrict__ srcp = edge_index;
    const int* __restrict__ dstp = edge_index + N_EDGES;
    const int stride = (gridDim.x - RS_RANGE_BLOCKS) * 256;
    for (int i = (blockIdx.x - RS_RANGE_BLOCKS) * 256 + threadIdx.x; i < N_EDGES;
         i += stride) {
        const int d = dstp[i];
        const int p = atomicAdd(&cursor[d], 1);
        sorted[p] = make_int2(i, (int)(((unsigned)srcp[i] << 16) | (unsigned)d));
    }
}

// ---------------------------------------------------------------------------
// Kernel 2: dst-sorted edge GEMM — EXACT Round-4 code (best measured:
// 126 us, VGPR 40, zero spill).
//   Register ledger (3 data points): bound 6 = 85 regs/wave budget -> clean;
//   bound 7 (73) and bound 8 (64) both spill (R9: FETCH +108MB; R5: +278MB).
//   2-deep sorted prefetch also spills (R8: +20MB). Occupancy and prefetch
//   levers are exhausted at this structure; do not touch without new theory.
// ---------------------------------------------------------------------------
__global__ __launch_bounds__(256, 6) void edge_gemm(
    const float* __restrict__ edge_attr,
    const float* __restrict__ W,
    const float* __restrict__ Y,
    const int*   __restrict__ range_start,
    const int2*  __restrict__ sorted,
    float*       __restrict__ out)
{
    __shared__ float CT[4][16][68];   // per-wave tile; quad bank-shift 16 -> free 2-way

    const int tid  = threadIdx.x;
    const int wave = tid >> 6;
    const int lane = tid & 63;
    const int col  = lane & 15;
    const int quad = lane >> 4;
    const int p    = wave & 1;        // col-half

    // B-frags for this wave's 64 cols: [2 kc][4 ns]
    short8 bfr[2][4];
    #pragma unroll
    for (int kc = 0; kc < 2; ++kc) {
        #pragma unroll
        for (int ns = 0; ns < 4; ++ns) {
            const int n = p * 64 + ns * 16 + col;
            const int krow = kc * 32 + quad * 8;
            short8 v;
            #pragma unroll
            for (int j = 0; j < 8; ++j)
                v[j] = (short)f2bf(W[(krow + j) * OUT_F + n]);
            bfr[kc][ns] = v;
        }
    }

    float* __restrict__ obase = out + p * 64 + lane;

    const int grange = blockIdx.x * 2 + (wave >> 1);
    const int stride = gridDim.x * 2;

    for (int rg = grange; rg < NRANGES; rg += stride) {
        const int eb = range_start[rg];
        const int ee = range_start[rg + 1];
        if (eb >= ee) continue;

        int   cur = -1;
        float s   = 0.f;

        // first tile's sorted entries + A-frags
        int2 me = sorted[min(eb + col, ee - 1)];
        short8 a[2];
        {
            const float* __restrict__ ar = edge_attr + (size_t)me.x * EDGE_F;
            #pragma unroll
            for (int kc = 0; kc < 2; ++kc)
                a[kc] = cvt8(*(const floatx4*)(ar + kc * 32 + quad * 8),
                             *(const floatx4*)(ar + kc * 32 + quad * 8 + 4));
        }

        for (int t0 = eb; t0 < ee; t0 += 16) {
            // ---- acc init = Y[src] gather for this wave's col-half ----
            floatx4 acc[4];
            #pragma unroll
            for (int r = 0; r < 4; ++r) {
                const int src = (int)((unsigned)__shfl(me.y, quad * 4 + r) >> 16);
                const float* __restrict__ yr = Y + (size_t)src * OUT_F + p * 64;
                #pragma unroll
                for (int ns = 0; ns < 4; ++ns)
                    acc[ns][r] = yr[ns * 16 + col];
            }

            // ---- MFMA: [16 edges x 64 cols], K=64 ----
            #pragma unroll
            for (int kc = 0; kc < 2; ++kc) {
                #pragma unroll
                for (int ns = 0; ns < 4; ++ns)
                    acc[ns] = __builtin_amdgcn_mfma_f32_16x16x32_bf16(a[kc], bfr[kc][ns], acc[ns], 0, 0, 0);
            }

            // ---- ReLU -> CT (pad rows write 0) ----
            #pragma unroll
            for (int r = 0; r < 4; ++r) {
                const bool rvalid = (t0 + quad * 4 + r) < ee;
                #pragma unroll
                for (int ns = 0; ns < 4; ++ns)
                    CT[wave][quad * 4 + r][ns * 16 + col] =
                        rvalid ? fmaxf(acc[ns][r], 0.f) : 0.f;
            }
            __builtin_amdgcn_wave_barrier();

            // ---- prefetch next tile's sorted entries (overlaps reduce) ----
            const int t1 = t0 + 16;
            int2 me2;
            if (t1 < ee) me2 = sorted[min(t1 + col, ee - 1)];

            // ---- reduce: batched LDS reads + uniform scalar flush ----
            float cv[16];
            #pragma unroll
            for (int m = 0; m < 16; ++m) cv[m] = CT[wave][m][lane];

            const int mez = me.y;
            #pragma unroll
            for (int m = 0; m < 16; ++m) {
                const int d = (int)((unsigned)__builtin_amdgcn_readlane(mez, m) & 0xffffu);
                if (d != cur) {
                    if (cur >= 0) obase[(size_t)cur * OUT_F] = s;
                    cur = d; s = 0.f;
                }
                s += cv[m];
            }
            cur = __builtin_amdgcn_readfirstlane(cur);
            __builtin_amdgcn_wave_barrier();

            // ---- next tile's A-frags ----
            if (t1 < ee) {
                me = me2;
                const float* __restrict__ ar = edge_attr + (size_t)me.x * EDGE_F;
                #pragma unroll
                for (int kc = 0; kc < 2; ++kc)
                    a[kc] = cvt8(*(const floatx4*)(ar + kc * 32 + quad * 8),
                                 *(const floatx4*)(ar + kc * 32 + quad * 8 + 4));
            }
        }
        if (cur >= 0) obase[(size_t)cur * OUT_F] = s;
    }
}

// ---------------------------------------------------------------------------
// Fallback (ws too small): atomic edge kernel
// ---------------------------------------------------------------------------
__global__ __launch_bounds__(256, 3) void edge_kernel_atomic(
    const float* __restrict__ edge_attr,
    const int*   __restrict__ edge_index,
    const float* __restrict__ W,
    const float* __restrict__ Y,
    float*       __restrict__ out)
{
    const int lane = threadIdx.x & 63;
    const int col  = lane & 15;
    const int quad = lane >> 4;

    short8 bfr[2][8];
    #pragma unroll
    for (int kc = 0; kc < 2; ++kc)
        #pragma unroll
        for (int ns = 0; ns < 8; ++ns) {
            const int n = ns * 16 + col;
            const int krow = kc * 32 + quad * 8;
            short8 v;
            #pragma unroll
            for (int j = 0; j < 8; ++j)
                v[j] = (short)f2bf(W[(krow + j) * OUT_F + n]);
            bfr[kc][ns] = v;
        }

    const int* __restrict__ srcp = edge_index;
    const int* __restrict__ dstp = edge_index + N_EDGES;

    const int gwave  = blockIdx.x * 4 + (threadIdx.x >> 6);
    const int nwaves = gridDim.x * 4;

    for (int t = gwave; t < N_EDGES / 16; t += nwaves) {
        const int e0 = t * 16;
        const float* __restrict__ ar = edge_attr + (size_t)(e0 + col) * EDGE_F;
        short8 a[2];
        #pragma unroll
        for (int kc = 0; kc < 2; ++kc)
            a[kc] = cvt8(*(const floatx4*)(ar + kc * 32 + quad * 8),
                         *(const floatx4*)(ar + kc * 32 + quad * 8 + 4));
        int sr[4], dr[4];
        #pragma unroll
        for (int r = 0; r < 4; ++r) {
            sr[r] = srcp[e0 + quad * 4 + r];
            dr[r] = dstp[e0 + quad * 4 + r];
        }
        floatx4 acc[8];
        #pragma unroll
        for (int ns = 0; ns < 8; ++ns)
            #pragma unroll
            for (int r = 0; r < 4; ++r)
                acc[ns][r] = Y[(size_t)sr[r] * OUT_F + ns * 16 + col];
        #pragma unroll
        for (int kc = 0; kc < 2; ++kc)
            #pragma unroll
            for (int ns = 0; ns < 8; ++ns)
                acc[ns] = __builtin_amdgcn_mfma_f32_16x16x32_bf16(a[kc], bfr[kc][ns], acc[ns], 0, 0, 0);
        #pragma unroll
        for (int ns = 0; ns < 8; ++ns)
            #pragma unroll
            for (int r = 0; r < 4; ++r) {
                const float v = acc[ns][r];
                if (v > 0.0f)
                    atomicAdd(out + (size_t)dr[r] * OUT_F + ns * 16 + col, v);
            }
    }
}

extern "C" void kernel_launch(void* const* d_in, const int* in_sizes, int n_in,
                              void* d_out, int out_size, void* d_ws, size_t ws_size,
                              hipStream_t stream) {
    const float* x          = (const float*)d_in[0];
    const int*   edge_index = (const int*)  d_in[1];
    const float* edge_attr  = (const float*)d_in[2];
    const float* W          = (const float*)d_in[3];
    const float* bias       = (const float*)d_in[4];
    float*       out        = (float*)d_out;

    // workspace layout
    float* Y          = (float*)d_ws;                          // 25.6 MB
    int2*  sorted     = (int2*)(Y + (size_t)N_NODES * OUT_F);  // 6.4 MB
    int*   hist       = (int*)(sorted + N_EDGES);
    int*   chunkSum   = hist + N_NODES;                        // (unused, layout kept)
    int*   chunkBase  = chunkSum + 256;                        // (unused, layout kept)
    int*   row_off    = chunkBase + 256;                       // N_NODES+1
    int*   cursor     = row_off + N_NODES + 1;                 // N_NODES
    int*   range_start= cursor + N_NODES;                      // NRANGES+1
    const size_t needed = (size_t)((char*)(range_start + NRANGES + 1) - (char*)d_ws);

    if (ws_size < needed) {
        hipMemsetAsync(out, 0, (size_t)out_size * sizeof(float), stream);
        node_hist_kernel<<<dim3(NODE_BLOCKS), dim3(256), 0, stream>>>(
            x, W, bias, Y, edge_index, (int*)nullptr);
        edge_kernel_atomic<<<dim3(1024), dim3(256), 0, stream>>>(edge_attr, edge_index, W, Y, out);
        return;
    }

    hipMemsetAsync(hist, 0, (size_t)N_NODES * sizeof(int), stream);
    node_hist_kernel<<<dim3(NODE_BLOCKS + HIST_BLOCKS), dim3(256), 0, stream>>>(
        x, W, bias, Y, edge_index, hist);
    scan_merged_kernel<<<dim3(NCH), dim3(256), 0, stream>>>(hist, row_off, cursor, out);
    range_scatter_kernel<<<dim3(RS_RANGE_BLOCKS + RS_SCATTER_BLOCKS), dim3(256), 0, stream>>>(
        row_off, edge_index, cursor, range_start, sorted);
    edge_gemm<<<dim3(EDGE_BLOCKS), dim3(256), 0, stream>>>(
        edge_attr, W, Y, range_start, sorted, out);
}

// Round 11
// 447.642 us; speedup vs baseline: 1.0951x; 1.0621x over previous
//
#include <hip/hip_runtime.h>
#include <hip/hip_bf16.h>

#define N_NODES 50000
#define N_EDGES 800000
#define NODE_F  128
#define EDGE_F  64
#define OUT_F   128

#define NCH ((N_NODES + 255) / 256)      // 196 scan chunks
// 768 blocks x 512 threads = 3072 wave-pairs; NRANGES = 6144 -> exactly 2
// ranges (~130 edges) per pair. Proportional boundaries snapped to row starts.
#define NRANGES 6144
#define EDGE_BLOCKS 768

typedef __attribute__((ext_vector_type(8))) short short8;
typedef __attribute__((ext_vector_type(4))) short short4v;
typedef __attribute__((ext_vector_type(4))) float floatx4;

__device__ __forceinline__ unsigned short f2bf(float f) {
    unsigned int u = __float_as_uint(f);
    u += 0x7fffu + ((u >> 16) & 1u);
    return (unsigned short)(u >> 16);
}

// packed RNE convert: 8 floats -> short8 bf16 via v_cvt_pk_bf16_f32
__device__ __forceinline__ short8 cvt8(floatx4 v0, floatx4 v1) {
    union { __hip_bfloat162 h[4]; short8 s; } u;
    u.h[0] = __float22bfloat162_rn(make_float2(v0[0], v0[1]));
    u.h[1] = __float22bfloat162_rn(make_float2(v0[2], v0[3]));
    u.h[2] = __float22bfloat162_rn(make_float2(v1[0], v1[1]));
    u.h[3] = __float22bfloat162_rn(make_float2(v1[2], v1[3]));
    return u.s;
}

// ---------------------------------------------------------------------------
// Kernel 1 (fused): blocks [0, NODE_BLOCKS) : Y[n][128] = x[n] @ W[64:192] + b
//                   blocks [NODE_BLOCKS, +HIST_BLOCKS) : dst-degree histogram
// ---------------------------------------------------------------------------
#define TILE_N1 32
#define N_NTILES ((N_NODES + TILE_N1 - 1) / TILE_N1)
#define LDS_STRIDE1 136
#define NODE_BLOCKS 782
#define HIST_BLOCKS 1024

__global__ __launch_bounds__(256, 4) void node_hist_kernel(
    const float* __restrict__ x,
    const float* __restrict__ W,
    const float* __restrict__ bias,
    float*       __restrict__ Y,
    const int*   __restrict__ edge_index,
    int*         __restrict__ hist)
{
    __shared__ __align__(16) unsigned short xs[TILE_N1][LDS_STRIDE1];

    if (blockIdx.x >= NODE_BLOCKS) {
        const int* __restrict__ dstp = edge_index + N_EDGES;
        const int stride = (gridDim.x - NODE_BLOCKS) * 256;
        for (int i = (blockIdx.x - NODE_BLOCKS) * 256 + threadIdx.x; i < N_EDGES;
             i += stride)
            atomicAdd(&hist[dstp[i]], 1);
        return;
    }

    const int tid  = threadIdx.x;
    const int wave = tid >> 6;
    const int lane = tid & 63;
    const int col  = lane & 15;
    const int quad = lane >> 4;
    const int wbase = wave * 32;

    const float* __restrict__ Wx = W + EDGE_F * OUT_F;

    short8 bfr[4][2];
    #pragma unroll
    for (int kc = 0; kc < 4; ++kc) {
        #pragma unroll
        for (int ns = 0; ns < 2; ++ns) {
            const int n = wbase + ns * 16 + col;
            const int krow = kc * 32 + quad * 8;
            short8 v;
            #pragma unroll
            for (int j = 0; j < 8; ++j)
                v[j] = (short)f2bf(Wx[(krow + j) * OUT_F + n]);
            bfr[kc][ns] = v;
        }
    }
    const float b0 = bias[wbase + col];
    const float b1 = bias[wbase + 16 + col];

    for (int tile = blockIdx.x; tile < N_NTILES; tile += NODE_BLOCKS) {
        const int n0 = tile * TILE_N1;
        {
            const int e   = tid >> 3;
            const int sub = tid & 7;
            const int node = n0 + e;
            const float* __restrict__ xr = x + (size_t)node * NODE_F;
            #pragma unroll
            for (int i = 0; i < 4; ++i) {
                const int fi = sub + 8 * i;
                floatx4 v = {0.f, 0.f, 0.f, 0.f};
                if (node < N_NODES) v = *(const floatx4*)(xr + fi * 4);
                union { __hip_bfloat162 h[2]; short4v s; } u;
                u.h[0] = __float22bfloat162_rn(make_float2(v[0], v[1]));
                u.h[1] = __float22bfloat162_rn(make_float2(v[2], v[3]));
                *(short4v*)&xs[e][fi * 4] = u.s;
            }
        }
        __syncthreads();

        floatx4 acc[2][2] = {};
        #pragma unroll
        for (int kc = 0; kc < 4; ++kc) {
            short8 a0 = *(const short8*)&xs[col     ][kc * 32 + quad * 8];
            short8 a1 = *(const short8*)&xs[16 + col][kc * 32 + quad * 8];
            acc[0][0] = __builtin_amdgcn_mfma_f32_16x16x32_bf16(a0, bfr[kc][0], acc[0][0], 0, 0, 0);
            acc[0][1] = __builtin_amdgcn_mfma_f32_16x16x32_bf16(a0, bfr[kc][1], acc[0][1], 0, 0, 0);
            acc[1][0] = __builtin_amdgcn_mfma_f32_16x16x32_bf16(a1, bfr[kc][0], acc[1][0], 0, 0, 0);
            acc[1][1] = __builtin_amdgcn_mfma_f32_16x16x32_bf16(a1, bfr[kc][1], acc[1][1], 0, 0, 0);
        }

        #pragma unroll
        for (int ms = 0; ms < 2; ++ms) {
            #pragma unroll
            for (int r = 0; r < 4; ++r) {
                const int m = ms * 16 + quad * 4 + r;
                const int node = n0 + m;
                if (node < N_NODES) {
                    float* yrow = Y + (size_t)node * OUT_F + wbase;
                    yrow[col]      = acc[ms][0][r] + b0;
                    yrow[16 + col] = acc[ms][1][r] + b1;
                }
            }
        }
        __syncthreads();
    }
}

// ---------------------------------------------------------------------------
// Counting sort by dst (scan1 + scan23: R4-proven; merged variant was a
// +20us regression — block c's chunk-base recompute was a serial c-pass loop)
// ---------------------------------------------------------------------------
__global__ void scan1_kernel(const int* __restrict__ hist, int* __restrict__ chunkSum) {
    __shared__ int s[256];
    const int c = blockIdx.x, t = threadIdx.x, idx = c * 256 + t;
    s[t] = (idx < N_NODES) ? hist[idx] : 0;
    __syncthreads();
    for (int off = 128; off > 0; off >>= 1) {
        if (t < off) s[t] += s[t + off];
        __syncthreads();
    }
    if (t == 0) chunkSum[c] = s[0];
}

__global__ void scan23_kernel(const int* __restrict__ hist, const int* __restrict__ chunkSum,
                              int* __restrict__ row_off, int* __restrict__ cursor,
                              float* __restrict__ out) {
    __shared__ int s[256];
    __shared__ int basev;
    const int c = blockIdx.x, t = threadIdx.x, idx = c * 256 + t;

    s[t] = (t < c) ? chunkSum[t] : 0;
    __syncthreads();
    for (int off = 128; off > 0; off >>= 1) {
        if (t < off) s[t] += s[t + off];
        __syncthreads();
    }
    if (t == 0) basev = s[0];
    __syncthreads();

    const int v = (idx < N_NODES) ? hist[idx] : 0;
    s[t] = v;
    __syncthreads();
    for (int off = 1; off < 256; off <<= 1) {
        int u = (t >= off) ? s[t - off] : 0;
        __syncthreads();
        s[t] += u;
        __syncthreads();
    }
    const int excl = s[t] - v + basev;
    if (idx < N_NODES) {
        row_off[idx] = excl;
        cursor[idx]  = excl;
        if (v == 0) {   // zero-degree node: edge_gemm never writes this row
            floatx4 z = {0.f, 0.f, 0.f, 0.f};
            float* o = out + (size_t)idx * OUT_F;
            #pragma unroll
            for (int i = 0; i < 32; ++i) *(floatx4*)(o + i * 4) = z;
        }
    }
    if (c == 0 && t == 0) row_off[N_NODES] = N_EDGES;
}

__device__ __forceinline__ int lbound(const int* __restrict__ ro, int target) {
    int lo = 0, hi = N_NODES;
    while (lo < hi) {
        const int mid = (lo + hi) >> 1;
        if (ro[mid] < target) lo = mid + 1; else hi = mid;
    }
    return lo;
}

// fused: blocks [0,32) compute range_start; blocks [32,+) scatter edges.
#define RS_RANGE_BLOCKS 32
#define RS_SCATTER_BLOCKS 2048
__global__ void range_scatter_kernel(const int* __restrict__ row_off,
                                     const int* __restrict__ edge_index,
                                     int* __restrict__ cursor,
                                     int* __restrict__ range_start,
                                     int2* __restrict__ sorted) {
    if (blockIdx.x < RS_RANGE_BLOCKS) {
        const int rg = blockIdx.x * 256 + threadIdx.x;
        if (rg <= NRANGES) {
            const int tgt = (int)((long long)rg * N_EDGES / NRANGES);
            range_start[rg] = row_off[lbound(row_off, tgt)];
        }
        return;
    }
    const int* __restrict__ srcp = edge_index;
    const int* __restrict__ dstp = edge_index + N_EDGES;
    const int stride = (gridDim.x - RS_RANGE_BLOCKS) * 256;
    for (int i = (blockIdx.x - RS_RANGE_BLOCKS) * 256 + threadIdx.x; i < N_EDGES;
         i += stride) {
        const int d = dstp[i];
        const int p = atomicAdd(&cursor[d], 1);
        sorted[p] = make_int2(i, (int)(((unsigned)srcp[i] << 16) | (unsigned)d));
    }
}

// ---------------------------------------------------------------------------
// Kernel 2 v5: dst-sorted edge GEMM, W-in-LDS + Y-gather pipelined into reduce.
//   Register ledger: R4 base sits at ~84/85 live (bound 6) -> ANY extra live
//   state spills (R1/R5/R8/R9). Fix: W frags -> LDS (WSf, pre-swizzled,
//   1x ds_read_b128 per MFMA B-operand, stride-16B conflict-free) frees 32
//   VGPRs. That headroom funds the pipeline: next tile's Y-gather issues into
//   the (dead) acc regs BEFORE the serial reduce -> ~500-1000cy L3 latency
//   hides under the ~300cy reduce. A-load stays after reduce (R4-style).
//   512-thread blocks (8 waves = 4 pairs) keep 24 waves/CU at 50KB LDS:
//   grid 768 = 256CU x 3, __launch_bounds__(512,6) -> 85 regs/wave budget.
//   asm memory clobber at iteration end stops LICM re-hoisting WSf reads
//   into 32 registers (which would recreate the spill).
// ---------------------------------------------------------------------------
__global__ __launch_bounds__(512, 6) void edge_gemm(
    const float* __restrict__ edge_attr,
    const float* __restrict__ W,
    const float* __restrict__ Y,
    const int*   __restrict__ range_start,
    const int2*  __restrict__ sorted,
    float*       __restrict__ out)
{
    __shared__ float CT[8][16][68];          // 34816 B; quad bank-shift -> free 2-way
    __shared__ short8 WSf[2][2][4][64];      // 16384 B; W frags [p][kc][ns][lane]

    const int tid  = threadIdx.x;
    const int wave = tid >> 6;
    const int lane = tid & 63;
    const int col  = lane & 15;
    const int quad = lane >> 4;
    const int p    = wave & 1;        // col-half

    // ---- stage W fragments into LDS (waves 0,1 only; same math as old bfr) ----
    if (wave < 2) {
        const int pp = wave;
        #pragma unroll
        for (int kc = 0; kc < 2; ++kc) {
            #pragma unroll
            for (int ns = 0; ns < 4; ++ns) {
                const int n = pp * 64 + ns * 16 + col;
                const int krow = kc * 32 + quad * 8;
                short8 v;
                #pragma unroll
                for (int j = 0; j < 8; ++j)
                    v[j] = (short)f2bf(W[(krow + j) * OUT_F + n]);
                WSf[pp][kc][ns][lane] = v;
            }
        }
    }
    __syncthreads();   // only block-wide sync; uniform for all waves

    float* __restrict__ obase = out + p * 64 + lane;

    const int pair   = wave >> 1;                 // 0..3
    const int grange = blockIdx.x * 4 + pair;
    const int stride = gridDim.x * 4;

    for (int rg = grange; rg < NRANGES; rg += stride) {
        const int eb = range_start[rg];
        const int ee = range_start[rg + 1];
        if (eb >= ee) continue;

        int   cur = -1;
        float s   = 0.f;

        // prologue: tile0 + tile1 meta; tile0 A-frags; tile0 Y into acc
        int2 me  = sorted[min(eb + col, ee - 1)];
        int2 meN = me;
        if (eb + 16 < ee) meN = sorted[min(eb + 16 + col, ee - 1)];

        short8 a[2];
        {
            const float* __restrict__ ar = edge_attr + (size_t)me.x * EDGE_F;
            #pragma unroll
            for (int kc = 0; kc < 2; ++kc)
                a[kc] = cvt8(*(const floatx4*)(ar + kc * 32 + quad * 8),
                             *(const floatx4*)(ar + kc * 32 + quad * 8 + 4));
        }
        floatx4 acc[4];
        #pragma unroll
        for (int r = 0; r < 4; ++r) {
            const int src = (int)((unsigned)__shfl(me.y, quad * 4 + r) >> 16);
            const float* __restrict__ yr = Y + (size_t)src * OUT_F + p * 64;
            #pragma unroll
            for (int ns = 0; ns < 4; ++ns)
                acc[ns][r] = yr[ns * 16 + col];
        }

        for (int t0 = eb; t0 < ee; t0 += 16) {
            const int t1 = t0 + 16;

            // ---- MFMA: B-frags streamed from LDS (ds_read_b128 each) ----
            #pragma unroll
            for (int kc = 0; kc < 2; ++kc) {
                #pragma unroll
                for (int ns = 0; ns < 4; ++ns)
                    acc[ns] = __builtin_amdgcn_mfma_f32_16x16x32_bf16(
                        a[kc], WSf[p][kc][ns][lane], acc[ns], 0, 0, 0);
            }

            // ---- ReLU -> CT (pad rows write 0); acc dead after this ----
            #pragma unroll
            for (int r = 0; r < 4; ++r) {
                const bool rvalid = (t0 + quad * 4 + r) < ee;
                #pragma unroll
                for (int ns = 0; ns < 4; ++ns)
                    CT[wave][quad * 4 + r][ns * 16 + col] =
                        rvalid ? fmaxf(acc[ns][r], 0.f) : 0.f;
            }
            __builtin_amdgcn_wave_barrier();

            // ---- prefetch tile t+2 meta ----
            int2 meNN = meN;
            if (t1 + 16 < ee) meNN = sorted[min(t1 + 16 + col, ee - 1)];

            // ---- issue NEXT tile's Y-gather into acc NOW (hides under reduce) ----
            if (t1 < ee) {
                #pragma unroll
                for (int r = 0; r < 4; ++r) {
                    const int srcN = (int)((unsigned)__shfl(meN.y, quad * 4 + r) >> 16);
                    const float* __restrict__ yrN = Y + (size_t)srcN * OUT_F + p * 64;
                    #pragma unroll
                    for (int ns = 0; ns < 4; ++ns)
                        acc[ns][r] = yrN[ns * 16 + col];
                }
            }

            // ---- reduce current tile: batched LDS reads + uniform flush ----
            float cv[16];
            #pragma unroll
            for (int m = 0; m < 16; ++m) cv[m] = CT[wave][m][lane];

            const int mez = me.y;
            #pragma unroll
            for (int m = 0; m < 16; ++m) {
                const int d = (int)((unsigned)__builtin_amdgcn_readlane(mez, m) & 0xffffu);
                if (d != cur) {
                    if (cur >= 0) obase[(size_t)cur * OUT_F] = s;
                    cur = d; s = 0.f;
                }
                s += cv[m];
            }
            cur = __builtin_amdgcn_readfirstlane(cur);
            __builtin_amdgcn_wave_barrier();
            asm volatile("" ::: "memory");   // pin WSf ds_reads in-loop (no LICM hoist)

            // ---- next tile's A-frags (immediate cvt; no f32 across reduce) ----
            if (t1 < ee) {
                const float* __restrict__ ar = edge_attr + (size_t)meN.x * EDGE_F;
                #pragma unroll
                for (int kc = 0; kc < 2; ++kc)
                    a[kc] = cvt8(*(const floatx4*)(ar + kc * 32 + quad * 8),
                                 *(const floatx4*)(ar + kc * 32 + quad * 8 + 4));
            }
            me = meN; meN = meNN;
        }
        if (cur >= 0) obase[(size_t)cur * OUT_F] = s;
    }
}

// ---------------------------------------------------------------------------
// Fallback (ws too small): atomic edge kernel
// ---------------------------------------------------------------------------
__global__ __launch_bounds__(256, 3) void edge_kernel_atomic(
    const float* __restrict__ edge_attr,
    const int*   __restrict__ edge_index,
    const float* __restrict__ W,
    const float* __restrict__ Y,
    float*       __restrict__ out)
{
    const int lane = threadIdx.x & 63;
    const int col  = lane & 15;
    const int quad = lane >> 4;

    short8 bfr[2][8];
    #pragma unroll
    for (int kc = 0; kc < 2; ++kc)
        #pragma unroll
        for (int ns = 0; ns < 8; ++ns) {
            const int n = ns * 16 + col;
            const int krow = kc * 32 + quad * 8;
            short8 v;
            #pragma unroll
            for (int j = 0; j < 8; ++j)
                v[j] = (short)f2bf(W[(krow + j) * OUT_F + n]);
            bfr[kc][ns] = v;
        }

    const int* __restrict__ srcp = edge_index;
    const int* __restrict__ dstp = edge_index + N_EDGES;

    const int gwave  = blockIdx.x * 4 + (threadIdx.x >> 6);
    const int nwaves = gridDim.x * 4;

    for (int t = gwave; t < N_EDGES / 16; t += nwaves) {
        const int e0 = t * 16;
        const float* __restrict__ ar = edge_attr + (size_t)(e0 + col) * EDGE_F;
        short8 a[2];
        #pragma unroll
        for (int kc = 0; kc < 2; ++kc)
            a[kc] = cvt8(*(const floatx4*)(ar + kc * 32 + quad * 8),
                         *(const floatx4*)(ar + kc * 32 + quad * 8 + 4));
        int sr[4], dr[4];
        #pragma unroll
        for (int r = 0; r < 4; ++r) {
            sr[r] = srcp[e0 + quad * 4 + r];
            dr[r] = dstp[e0 + quad * 4 + r];
        }
        floatx4 acc[8];
        #pragma unroll
        for (int ns = 0; ns < 8; ++ns)
            #pragma unroll
            for (int r = 0; r < 4; ++r)
                acc[ns][r] = Y[(size_t)sr[r] * OUT_F + ns * 16 + col];
        #pragma unroll
        for (int kc = 0; kc < 2; ++kc)
            #pragma unroll
            for (int ns = 0; ns < 8; ++ns)
                acc[ns] = __builtin_amdgcn_mfma_f32_16x16x32_bf16(a[kc], bfr[kc][ns], acc[ns], 0, 0, 0);
        #pragma unroll
        for (int ns = 0; ns < 8; ++ns)
            #pragma unroll
            for (int r = 0; r < 4; ++r) {
                const float v = acc[ns][r];
                if (v > 0.0f)
                    atomicAdd(out + (size_t)dr[r] * OUT_F + ns * 16 + col, v);
            }
    }
}

extern "C" void kernel_launch(void* const* d_in, const int* in_sizes, int n_in,
                              void* d_out, int out_size, void* d_ws, size_t ws_size,
                              hipStream_t stream) {
    const float* x          = (const float*)d_in[0];
    const int*   edge_index = (const int*)  d_in[1];
    const float* edge_attr  = (const float*)d_in[2];
    const float* W          = (const float*)d_in[3];
    const float* bias       = (const float*)d_in[4];
    float*       out        = (float*)d_out;

    // workspace layout
    float* Y          = (float*)d_ws;                          // 25.6 MB
    int2*  sorted     = (int2*)(Y + (size_t)N_NODES * OUT_F);  // 6.4 MB
    int*   hist       = (int*)(sorted + N_EDGES);
    int*   chunkSum   = hist + N_NODES;
    int*   chunkBase  = chunkSum + 256;
    int*   row_off    = chunkBase + 256;                       // N_NODES+1
    int*   cursor     = row_off + N_NODES + 1;                 // N_NODES
    int*   range_start= cursor + N_NODES;                      // NRANGES+1
    const size_t needed = (size_t)((char*)(range_start + NRANGES + 1) - (char*)d_ws);

    if (ws_size < needed) {
        hipMemsetAsync(out, 0, (size_t)out_size * sizeof(float), stream);
        node_hist_kernel<<<dim3(NODE_BLOCKS), dim3(256), 0, stream>>>(
            x, W, bias, Y, edge_index, (int*)nullptr);
        edge_kernel_atomic<<<dim3(1024), dim3(256), 0, stream>>>(edge_attr, edge_index, W, Y, out);
        return;
    }

    hipMemsetAsync(hist, 0, (size_t)N_NODES * sizeof(int), stream);
    node_hist_kernel<<<dim3(NODE_BLOCKS + HIST_BLOCKS), dim3(256), 0, stream>>>(
        x, W, bias, Y, edge_index, hist);
    scan1_kernel  <<<dim3(NCH), dim3(256), 0, stream>>>(hist, chunkSum);
    scan23_kernel <<<dim3(NCH), dim3(256), 0, stream>>>(hist, chunkSum, row_off, cursor, out);
    range_scatter_kernel<<<dim3(RS_RANGE_BLOCKS + RS_SCATTER_BLOCKS), dim3(256), 0, stream>>>(
        row_off, edge_index, cursor, range_start, sorted);
    edge_gemm<<<dim3(EDGE_BLOCKS), dim3(512), 0, stream>>>(
        edge_attr, W, Y, range_start, sorted, out);
}